// Round 3
// baseline (709.295 us; speedup 1.0000x reference)
//
#include <hip/hip_runtime.h>
#include <hip/hip_bf16.h>
#include <math.h>

#define N_NODES 500000
#define DIM 256
#define ADIM 64
#define NG 512
#define TILE 32
#define NTILES 15625      // 500000 / 32 exact
#define GRID_F 512        // 2 blocks/CU (LDS-bound)

// dynamic LDS layout (bytes)
#define OFF_XSF   0        // float [2][32][256] = 65536
#define OFF_REDP  65536    // float [4][256]     = 4096
#define OFF_SACC  69632    // float [4][32]      = 512
#define OFF_PBUF  70144    // float [32]         = 128
#define OFF_GBUF  70272    // int   [32]         = 128
#define SMEM_BYTES 70656

typedef __attribute__((ext_vector_type(8))) short short8;
typedef __attribute__((ext_vector_type(4))) float floatx4;

// raw barrier: waits LDS ops only, does NOT drain vmcnt -> global_load_lds
// prefetch stays in flight across it
#define BAR() asm volatile("s_waitcnt lgkmcnt(0)\n\ts_barrier" ::: "memory")
#define VMWAIT0() asm volatile("s_waitcnt vmcnt(0)" ::: "memory")

__device__ inline unsigned short f2bf(float f) {
    union { float f; unsigned int u; } v; v.f = f;
    unsigned int u = v.u;
    unsigned int r = u + 0x7FFFu + ((u >> 16) & 1u);   // RNE
    return (unsigned short)(r >> 16);
}

// packed fp32 pair -> 2x bf16 (RNE) in one u32 (v_cvt_pk_bf16_f32)
__device__ inline unsigned pk_bf2(float a, float b) {
    __hip_bfloat162 h = __float22bfloat162_rn(make_float2(a, b));
    union { __hip_bfloat162 h; unsigned u; } cv; cv.h = h;
    return cv.u;
}

__device__ inline float tanh_fast(float xv) {
    float e = __expf(2.0f * fabsf(xv));
    float r = 1.0f - 2.0f * __builtin_amdgcn_rcpf(e + 1.0f);
    return copysignf(r, xv);
}

// DPP row-of-16 sum (no LDS traffic): xor1, xor2 via quad_perm; +ror4; +ror8
template <int CTRL>
__device__ inline float dpp_add(float v) {
    union { float f; int i; } a, b;
    a.f = v;
    b.i = __builtin_amdgcn_update_dpp(0, a.i, CTRL, 0xF, 0xF, true);
    return v + b.f;
}
__device__ inline float row16_sum(float v) {
    v = dpp_add<0xB1>(v);    // quad_perm(1,0,3,2)  (xor 1)
    v = dpp_add<0x4E>(v);    // quad_perm(2,3,0,1)  (xor 2)
    v = dpp_add<0x124>(v);   // row_ror:4
    v = dpp_add<0x128>(v);   // row_ror:8
    return v;
}

// ---------------- prep: transpose W_out, W_att->bf16, c=||ctx||_1, zero accum/ssum
__global__ __launch_bounds__(256) void k_prep(const float* __restrict__ W_out,
                                              const float* __restrict__ W_att,
                                              const float* __restrict__ ctx,
                                              float* __restrict__ Wt_out,
                                              unsigned short* __restrict__ Wbf,
                                              float* __restrict__ cnorm,
                                              float* __restrict__ zero_base) {
    int b = blockIdx.x, t = threadIdx.x;
    if (b < 256) {
        int idx = b * 256 + t;
        int o = idx >> 8, d = idx & 255;
        Wt_out[d * DIM + o] = W_out[idx];
    } else if (b < 320) {
        int idx = (b - 256) * 256 + t;
        Wbf[idx] = f2bf(W_att[idx]);
    } else if (b < 834) {
        int idx = (b - 320) * 256 + t;   // 514*256 == 131584 covers accum+ssum
        zero_base[idx] = 0.f;
    } else if (t == 0) {
        float s = 0.f;
        for (int k = 0; k < ADIM; ++k) s += fabsf(ctx[k]);
        *cnorm = s;
    }
}

// stage one 32-node tile: global fp32 -> LDS fp32 via global_load_lds (16B/lane,
// fire-and-forget). Source chunk index XOR'd with (row&7) so that MFMA fragment
// reads spread uniformly over the 8 bank-slots (physical chunk = logical ^ (row&7)).
__device__ inline void stage_tile(const float* __restrict__ x, float* xsf_buf,
                                  int tile, int wave, int lane) {
#pragma unroll
    for (int r = 0; r < 8; ++r) {
        const int row = wave * 8 + r;            // row & 7 == r  (wave*8 multiple of 8)
        const float* gsrc = x + (size_t)(tile * TILE + row) * DIM + ((lane ^ r) << 2);
        __builtin_amdgcn_global_load_lds(
            (const __attribute__((address_space(1))) unsigned int*)gsrc,
            (__attribute__((address_space(3))) unsigned int*)(xsf_buf + row * DIM),
            16, 0, 0);
    }
}

// ---------------- fused streaming kernel: scores (MFMA) + exp + pooling.
__global__ __launch_bounds__(256) void k_fused(const float* __restrict__ x,
                                               const unsigned short* __restrict__ Wbf,
                                               const float* __restrict__ b_att,
                                               const float* __restrict__ ctx,
                                               const int* __restrict__ batch,
                                               const float* __restrict__ cnorm,
                                               float* __restrict__ accum,   // [NG][DIM]
                                               float* __restrict__ ssum) {  // [NG]
    extern __shared__ __align__(16) char smem[];
    float* xsf  = (float*)(smem + OFF_XSF);    // [2][32][256]
    float* redp = (float*)(smem + OFF_REDP);   // [4][256]
    float* sacc = (float*)(smem + OFF_SACC);   // [4][32]
    float* pbuf = (float*)(smem + OFF_PBUF);   // [32]
    int*   gbuf = (int*)(smem + OFF_GBUF);     // [32]

    const int t = threadIdx.x;
    const int wave = t >> 6;
    const int lane = t & 63;
    const int quad = lane >> 4;
    const int lcol = lane & 15;
    const int m = lcol & 7;                    // read-side swizzle key for MFMA rows
    const float cn = *cnorm;

    const int b = blockIdx.x;
    const int q = NTILES / GRID_F, r = NTILES % GRID_F;
    const int t0 = b * q + min(b, r);
    const int t1 = t0 + q + (b < r ? 1 : 0);

    // B fragments (bf16 W_att, L2-resident)
    short8 bfrag[8];
    {
        const unsigned short* wr = Wbf + (size_t)(16 * wave + lcol) * DIM + quad * 8;
#pragma unroll
        for (int s = 0; s < 8; ++s) bfrag[s] = *(const short8*)(wr + s * 32);
    }

    const float ctxv = ctx[16 * wave + lcol];
    const float bv = b_att[16 * wave + lcol];

    float4 a4 = make_float4(0.f, 0.f, 0.f, 0.f);  // pool acc, dims 4*lane..+4
    float s_acc = 0.f;                            // sum-of-p (t<32)
    int cur_g = -1;
    int cur = 0;

    auto FLUSH = [&](int gf) {
        *(float4*)(redp + wave * DIM + (lane << 2)) = a4;
        BAR();
        float rsum = (redp[t] + redp[DIM + t]) + (redp[2 * DIM + t] + redp[3 * DIM + t]);
        atomicAdd(&accum[(size_t)gf * DIM + t], rsum);
        if (t < 64) {
            float sp = (t < 32) ? s_acc : 0.f;
            sp += __shfl_xor(sp, 1);  sp += __shfl_xor(sp, 2);
            sp += __shfl_xor(sp, 4);  sp += __shfl_xor(sp, 8);
            sp += __shfl_xor(sp, 16);
            if (t == 0) atomicAdd(&ssum[gf], sp);
        }
        BAR();
    };

    // ---- prologue: stage tile t0 into buffer 0
    stage_tile(x, xsf, t0, wave, lane);
    VMWAIT0();
    BAR();

    for (int ti = t0; ti < t1; ++ti) {
        const bool haveNext = (ti + 1 < t1);
        float* xcur = xsf + cur * (TILE * DIM);

        // ---- fire-and-forget prefetch of next tile (full-iteration distance)
        if (haveNext) stage_tile(x, xsf + (cur ^ 1) * (TILE * DIM), ti + 1, wave, lane);
        const int bval = batch[ti * TILE + (t & 31)];

        // ---- MFMA: logits[node][attncol], bf16 cvt at fragment-read time
        floatx4 acc0 = (floatx4)0.f, acc1 = (floatx4)0.f;
#pragma unroll
        for (int s = 0; s < 8; ++s) {
            const int q0 = s * 8 + quad * 2;
#pragma unroll
            for (int mt = 0; mt < 2; ++mt) {
                const float* rowp = xcur + (mt * 16 + lcol) * DIM;
                float4 f0 = *(const float4*)(rowp + (((q0    ) ^ m) << 2));
                float4 f1 = *(const float4*)(rowp + (((q0 + 1) ^ m) << 2));
                union { short8 v; unsigned u[4]; } au;
                au.u[0] = pk_bf2(f0.x, f0.y); au.u[1] = pk_bf2(f0.z, f0.w);
                au.u[2] = pk_bf2(f1.x, f1.y); au.u[3] = pk_bf2(f1.z, f1.w);
                if (mt == 0) acc0 = __builtin_amdgcn_mfma_f32_16x16x32_bf16(au.v, bfrag[s], acc0, 0, 0, 0);
                else         acc1 = __builtin_amdgcn_mfma_f32_16x16x32_bf16(au.v, bfrag[s], acc1, 0, 0, 0);
            }
        }

        // ---- scores: DPP row-of-16 reduce of ctx*tanh
#pragma unroll
        for (int mt = 0; mt < 2; ++mt) {
#pragma unroll
            for (int r4 = 0; r4 < 4; ++r4) {
                float av = (mt == 0) ? acc0[r4] : acc1[r4];
                float v = row16_sum(ctxv * tanh_fast(av + bv));
                if (lcol == 0) sacc[wave * 32 + mt * 16 + quad * 4 + r4] = v;
            }
        }
        BAR();   // sacc visible

        if (t < 32) {
            float sres = (sacc[t] + sacc[32 + t]) + (sacc[64 + t] + sacc[96 + t]);
            pbuf[t] = __expf(sres - cn);   // |s| <= cn: no segment max needed
            gbuf[t] = bval;
        }
        BAR();   // pbuf/gbuf visible

        // ---- pooling from fp32 LDS tile; register accumulate, flush on seg change
        const int g0 = gbuf[0];
        const int g1 = gbuf[31];
        if (cur_g < 0) cur_g = g0;
        for (int g = cur_g; g <= g1; ++g) {
#pragma unroll
            for (int j = 0; j < 8; ++j) {
                const int i = (wave << 3) + j;             // i & 7 == j
                const float wp = (gbuf[i] == g) ? pbuf[i] : 0.f;   // wave-uniform
                if (wp != 0.f) {
                    const float4 v = *(const float4*)(xcur + i * DIM + ((lane ^ j) << 2));
                    a4.x += wp * v.x;
                    a4.y += wp * v.y;
                    a4.z += wp * v.z;
                    a4.w += wp * v.w;
                }
            }
            if (t < 32) s_acc += (gbuf[t] == g) ? pbuf[t] : 0.f;
            if (g < g1) {
                FLUSH(g);
                a4 = make_float4(0.f, 0.f, 0.f, 0.f);
                s_acc = 0.f;
            }
        }
        cur_g = g1;

        // ---- next tile landed? (only drain point for the async loads)
        if (haveNext) VMWAIT0();
        BAR();   // next buffer ready; this buffer free for overwrite
        cur ^= 1;
    }
    FLUSH(cur_g);
}

// ---------------- out = (accum/ssum) @ W_out^T + b_out
__global__ __launch_bounds__(256) void k_out(const float* __restrict__ accum,
                                             const float* __restrict__ ssum,
                                             const float* __restrict__ WtOut,
                                             const float* __restrict__ b_out,
                                             float* __restrict__ out) {
    int g = blockIdx.x;
    int t = threadIdx.x;
    __shared__ float pl[256];
    float inv = 1.0f / (ssum[g] + 1e-20f);
    pl[t] = accum[(size_t)g * DIM + t] * inv;
    __syncthreads();
    float acc = b_out[t];
#pragma unroll 4
    for (int d = 0; d < DIM; ++d) acc += pl[d] * WtOut[d * DIM + t];
    out[(size_t)g * DIM + t] = acc;
}

extern "C" void kernel_launch(void* const* d_in, const int* in_sizes, int n_in,
                              void* d_out, int out_size, void* d_ws, size_t ws_size,
                              hipStream_t stream) {
    (void)in_sizes; (void)n_in; (void)out_size; (void)ws_size;
    const float* x     = (const float*)d_in[0];
    const int*   batch = (const int*)d_in[1];
    const float* W_att = (const float*)d_in[2];
    const float* b_att = (const float*)d_in[3];
    const float* ctx   = (const float*)d_in[4];
    const float* W_out = (const float*)d_in[5];
    const float* b_out = (const float*)d_in[6];
    float* out = (float*)d_out;

    float* accum = (float*)d_ws;                         // 131072
    float* ssum  = accum + 131072;                       // 512
    float* Wt    = ssum + 512;                           // 65536
    unsigned short* Wbf = (unsigned short*)(Wt + 65536); // 16384 ushort
    float* cnorm = (float*)(Wbf + 16384);                // 1

    hipFuncSetAttribute((const void*)k_fused,
                        hipFuncAttributeMaxDynamicSharedMemorySize, SMEM_BYTES);

    k_prep<<<dim3(835), dim3(256), 0, stream>>>(W_out, W_att, ctx, Wt, Wbf, cnorm, accum);
    k_fused<<<dim3(GRID_F), dim3(256), SMEM_BYTES, stream>>>(x, Wbf, b_att, ctx, batch, cnorm, accum, ssum);
    k_out<<<dim3(NG), dim3(256), 0, stream>>>(accum, ssum, Wt, b_out, out);
}